// Round 5
// baseline (531.780 us; speedup 1.0000x reference)
//
#include <hip/hip_runtime.h>
#include <hip/hip_bf16.h>

typedef unsigned short u16;
typedef unsigned long long u64;
typedef __attribute__((ext_vector_type(4))) float f32x4;
typedef __attribute__((ext_vector_type(8))) __bf16 bf16x8;
typedef __attribute__((ext_vector_type(8))) u16 u16x8;

#define DEV __device__ __forceinline__
#define MFMA(a, b, c) __builtin_amdgcn_mfma_f32_16x16x32_bf16(a, b, c, 0, 0, 0)

// B=4, S=1024, D=1024, H=16, DK=DV=64, M=B*S=4096

DEV u16 f2bf(float x) {
  unsigned u = __builtin_bit_cast(unsigned, x);
  u += 0x7fffu + ((u >> 16) & 1u);
  return (u16)(u >> 16);
}
DEV float bf2f(u16 h) {
  unsigned u = ((unsigned)h) << 16;
  return __builtin_bit_cast(float, u);
}
DEV bf16x8 frag8(const u16* p) {
  return __builtin_bit_cast(bf16x8, *(const u16x8*)p);
}
// async global->LDS, 16B per lane; lds base must be the wave-uniform chunk base
DEV void gload16(u16* lds, const u16* g) {
  __builtin_amdgcn_global_load_lds((const __attribute__((address_space(1))) void*)g,
                                   (__attribute__((address_space(3))) void*)lds, 16, 0, 0);
}

// ---------------- prep: transpose + hi/lo-split weights into [N][K] bf16 ----------------
__global__ __launch_bounds__(256) void prep_weights(
    const float* __restrict__ Wq, const float* __restrict__ Wk,
    const float* __restrict__ Wv, const float* __restrict__ Wp,
    u16* __restrict__ wqh, u16* __restrict__ wql,
    u16* __restrict__ wkh, u16* __restrict__ wkl,
    u16* __restrict__ wvh, u16* __restrict__ wph) {
  __shared__ float tile[64][65];
  const int k0 = blockIdx.x * 64;
  const int h = blockIdx.y;
  const int z = blockIdx.z;
  const float* src;
  u16* dhi;
  u16* dlo = nullptr;
  int hs, rs;
  if (z == 0)      { src = Wq; dhi = wqh; dlo = wql; hs = 65536; rs = 64; }
  else if (z == 1) { src = Wk; dhi = wkh; dlo = wkl; hs = 65536; rs = 64; }
  else if (z == 2) { src = Wv; dhi = wvh;            hs = 65536; rs = 64; }
  else             { src = Wp; dhi = wph;            hs = 64;    rs = 1024; }
  const int t = threadIdx.x;
#pragma unroll
  for (int i = 0; i < 16; ++i) {
    int kk = i * 4 + (t >> 6), nn = t & 63;
    tile[kk][nn] = src[h * hs + (k0 + kk) * rs + nn];
  }
  __syncthreads();
#pragma unroll
  for (int i = 0; i < 16; ++i) {
    int nn = i * 4 + (t >> 6), kk = t & 63;
    float x = tile[kk][nn];
    u16 hi = f2bf(x);
    int idx = (h * 64 + nn) * 1024 + k0 + kk;
    dhi[idx] = hi;
    if (dlo) dlo[idx] = f2bf(x - bf2f(hi));
  }
}

// ---------------- prep: pack mask rows into u64 bit-words ----------------
__global__ __launch_bounds__(256) void pack_mask(const int* __restrict__ mask,
                                                 u64* __restrict__ mp) {
  int g = blockIdx.x * 4 + (threadIdx.x >> 6);  // word id 0..16383
  int lane = threadIdx.x & 63;
  int v = mask[(g >> 4) * 1024 + (g & 15) * 64 + lane];
  u64 bits = __ballot(v != 0);
  if (lane == 0) mp[g] = bits;
}

// ---------------- prep: split activations fp32 -> hi/lo bf16 ----------------
// z=0: querys -> Xqh/Xql ; z=1: keys -> Xkh/Xkl ; z=2: values -> Xvh (hi only)
__global__ __launch_bounds__(256) void split_x(
    const float* __restrict__ q, const float* __restrict__ k,
    const float* __restrict__ v, u16* __restrict__ qh, u16* __restrict__ ql,
    u16* __restrict__ kh, u16* __restrict__ kl, u16* __restrict__ vh) {
  const int z = blockIdx.y;
  const float* src = (z == 0) ? q : (z == 1) ? k : v;
  u16* dh = (z == 0) ? qh : (z == 1) ? kh : vh;
  u16* dl = (z == 0) ? ql : kl;
  const bool split = (z < 2);
  const long base = (long)(blockIdx.x * 256 + threadIdx.x) * 8;
  f32x4 v0 = *(const f32x4*)&src[base];
  f32x4 v1 = *(const f32x4*)&src[base + 4];
  u16x8 hi, lo;
#pragma unroll
  for (int e = 0; e < 4; ++e) {
    u16 h0 = f2bf(v0[e]), h1 = f2bf(v1[e]);
    hi[e] = h0;
    hi[4 + e] = h1;
    lo[e] = f2bf(v0[e] - bf2f(h0));
    lo[4 + e] = f2bf(v1[e] - bf2f(h1));
  }
  *(u16x8*)&dh[base] = hi;
  if (split) *(u16x8*)&dl[base] = lo;
}

// ---------------- fused QKV projection GEMM (global_load_lds staging) ----------------
// z=0: Xq @ Wq -> split Qh/Ql ; z=1: Xk @ Wk -> split Kh/Kl
// z=2: Xv @ Wv -> plain bf16 transposed Vt[bh][dv][s]
__global__ __launch_bounds__(256, 4) void proj_fused(
    const u16* __restrict__ Xqh, const u16* __restrict__ Xql,
    const u16* __restrict__ Xkh, const u16* __restrict__ Xkl,
    const u16* __restrict__ Xvh, const u16* __restrict__ wqh,
    const u16* __restrict__ wql, const u16* __restrict__ wkh,
    const u16* __restrict__ wkl, const u16* __restrict__ wvh,
    const float* __restrict__ bq, const float* __restrict__ bk,
    const float* __restrict__ bv, u16* __restrict__ Qh, u16* __restrict__ Ql,
    u16* __restrict__ Kh, u16* __restrict__ Kl, u16* __restrict__ Vt) {
  __shared__ alignas(16) u16 Ah[128 * 32];
  __shared__ alignas(16) u16 Al[128 * 32];
  __shared__ alignas(16) u16 Bh[128 * 32];
  __shared__ alignas(16) u16 Bl[128 * 32];
  const int z = blockIdx.z;
  const bool split = (z < 2);
  const u16* Ah_src = (z == 0) ? Xqh : (z == 1) ? Xkh : Xvh;
  const u16* Al_src = (z == 0) ? Xql : Xkl;
  const u16* Bh_src = (z == 0) ? wqh : (z == 1) ? wkh : wvh;
  const u16* Bl_src = (z == 0) ? wql : wkl;
  const float* bias = (z == 0) ? bq : (z == 1) ? bk : bv;
  u16* Oh = (z == 0) ? Qh : (z == 1) ? Kh : Vt;
  u16* Ol = (z == 0) ? Ql : Kl;

  const int m0 = blockIdx.x * 128, n0 = blockIdx.y * 128;
  const int t = threadIdx.x, w = t >> 6, l = t & 63;
  const int wr = w >> 1, wc = w & 1, lr = l & 15, lq = l >> 4;
  const int srow = l >> 2, scol = (l & 3) * 8;  // staging lane coords
  f32x4 acc[4][4];
#pragma unroll
  for (int i = 0; i < 4; ++i)
#pragma unroll
    for (int j = 0; j < 4; ++j) acc[i][j] = (f32x4){0.f, 0.f, 0.f, 0.f};

  for (int ks = 0; ks < 32; ++ks) {
    const int k0 = ks * 32;
    // stage: 8KB/tile = 8 chunks of 1KB; wave w issues chunks {2w, 2w+1}
#pragma unroll
    for (int i = 0; i < 2; ++i) {
      const int ci = w * 2 + i;
      const int rr = ci * 16 + srow;
      gload16(&Ah[ci * 512], &Ah_src[(m0 + rr) * 1024 + k0 + scol]);
      gload16(&Bh[ci * 512], &Bh_src[(n0 + rr) * 1024 + k0 + scol]);
      if (split) {
        gload16(&Al[ci * 512], &Al_src[(m0 + rr) * 1024 + k0 + scol]);
        gload16(&Bl[ci * 512], &Bl_src[(n0 + rr) * 1024 + k0 + scol]);
      }
    }
    __syncthreads();
    bf16x8 ah[4], al[4];
#pragma unroll
    for (int mi = 0; mi < 4; ++mi) {
      int row = wr * 64 + mi * 16 + lr;
      ah[mi] = frag8(&Ah[row * 32 + lq * 8]);
      if (split) al[mi] = frag8(&Al[row * 32 + lq * 8]);
    }
    if (split) {
#pragma unroll
      for (int nj = 0; nj < 4; ++nj) {
        int col = wc * 64 + nj * 16 + lr;
        bf16x8 bh = frag8(&Bh[col * 32 + lq * 8]);
        bf16x8 bl = frag8(&Bl[col * 32 + lq * 8]);
#pragma unroll
        for (int mi = 0; mi < 4; ++mi) {
          acc[mi][nj] = MFMA(ah[mi], bh, acc[mi][nj]);
          acc[mi][nj] = MFMA(ah[mi], bl, acc[mi][nj]);
          acc[mi][nj] = MFMA(al[mi], bh, acc[mi][nj]);
        }
      }
    } else {
#pragma unroll
      for (int nj = 0; nj < 4; ++nj) {
        int col = wc * 64 + nj * 16 + lr;
        bf16x8 bh = frag8(&Bh[col * 32 + lq * 8]);
#pragma unroll
        for (int mi = 0; mi < 4; ++mi) acc[mi][nj] = MFMA(ah[mi], bh, acc[mi][nj]);
      }
    }
    __syncthreads();
  }
  // epilogue: add bias, split-store (z<2) or transpose-store (z==2)
#pragma unroll
  for (int nj = 0; nj < 4; ++nj) {
    int n = n0 + wc * 64 + nj * 16 + lr;
    float bb = bias[n];
    int h = n >> 6, dk = n & 63;
#pragma unroll
    for (int mi = 0; mi < 4; ++mi) {
#pragma unroll
      for (int j = 0; j < 4; ++j) {
        int m = m0 + wr * 64 + mi * 16 + lq * 4 + j;
        int b = m >> 10, s = m & 1023;
        float x = acc[mi][nj][j] + bb;
        if (split) {
          int idx = ((b * 16 + h) * 1024 + s) * 64 + dk;
          u16 hh = f2bf(x);
          Oh[idx] = hh;
          Ol[idx] = f2bf(x - bf2f(hh));
        } else {
          int idx = ((b * 16 + h) * 64 + dk) * 1024 + s;
          Oh[idx] = f2bf(x);
        }
      }
    }
  }
}

// ---------------- flash attention: 1 block per (b,h, 64-row q-tile) ----------------
// T14 async-STAGE: issue tile t+1 global loads under tile t compute.
__global__ __launch_bounds__(256, 4) void attn_kernel(
    const u16* __restrict__ Qh, const u16* __restrict__ Ql,
    const u16* __restrict__ Kh, const u16* __restrict__ Kl,
    const u16* __restrict__ Vt, const u64* __restrict__ mp,
    u16* __restrict__ Oc) {
  __shared__ alignas(16) u16 Ks_h[64 * 72];
  __shared__ alignas(16) u16 Ks_l[64 * 72];
  __shared__ alignas(16) u16 Vs[64 * 72];
  __shared__ alignas(16) u16 Ps[4][16 * 72];
  __shared__ u64 mw[64];
  const int bid = blockIdx.x;
  const int bh = bid >> 4, qt = bid & 15, q0 = qt * 64;
  const int t = threadIdx.x, w = t >> 6, l = t & 63;
  const int lr = l & 15, lq = l >> 4;
  const int qrow = q0 + w * 16 + lr;
  const int rr = t >> 2, c0 = (t & 3) * 8;

  bf16x8 qh[2], qlo[2];
#pragma unroll
  for (int d = 0; d < 2; ++d) {
    int off = (bh * 1024 + qrow) * 64 + d * 32 + lq * 8;
    qh[d] = frag8(&Qh[off]);
    qlo[d] = frag8(&Ql[off]);
  }
  f32x4 o[4];
#pragma unroll
  for (int dv = 0; dv < 4; ++dv) o[dv] = (f32x4){0.f, 0.f, 0.f, 0.f};
  float mr[4] = {-1e30f, -1e30f, -1e30f, -1e30f};
  float lsum[4] = {0.f, 0.f, 0.f, 0.f};

  // prefetch registers for the next tile
  u16x8 rKh[2], rKl[2], rVs[2];
  u64 rMw = 0;
  auto issue = [&](int kt) {
    const int k0 = kt * 64;
#pragma unroll
    for (int half = 0; half < 2; ++half) {
      int c = c0 + half * 32;
      rKh[half] = *(const u16x8*)&Kh[(bh * 1024 + k0 + rr) * 64 + c];
      rKl[half] = *(const u16x8*)&Kl[(bh * 1024 + k0 + rr) * 64 + c];
      rVs[half] = *(const u16x8*)&Vt[(bh * 64 + rr) * 1024 + k0 + c];
    }
    if (t < 64) rMw = mp[(q0 + t) * 16 + kt];
  };

  issue(0);
  for (int kt = 0; kt < 16; ++kt) {
    // write phase: prefetched regs -> LDS
#pragma unroll
    for (int half = 0; half < 2; ++half) {
      int c = c0 + half * 32;
      *(u16x8*)&Ks_h[rr * 72 + c] = rKh[half];
      *(u16x8*)&Ks_l[rr * 72 + c] = rKl[half];
      *(u16x8*)&Vs[rr * 72 + c] = rVs[half];
    }
    if (t < 64) mw[t] = rMw;
    __syncthreads();
    if (kt < 15) issue(kt + 1);  // latency hides under compute below
    // scores: S[16q x 64key] via 3-term split MFMA
    f32x4 s[4];
#pragma unroll
    for (int kb = 0; kb < 4; ++kb) {
      f32x4 a = (f32x4){0.f, 0.f, 0.f, 0.f};
#pragma unroll
      for (int d = 0; d < 2; ++d) {
        bf16x8 kfh = frag8(&Ks_h[(kb * 16 + lr) * 72 + d * 32 + lq * 8]);
        bf16x8 kfl = frag8(&Ks_l[(kb * 16 + lr) * 72 + d * 32 + lq * 8]);
        a = MFMA(qh[d], kfh, a);
        a = MFMA(qh[d], kfl, a);
        a = MFMA(qlo[d], kfh, a);
      }
      s[kb] = a;
    }
    // mask + online softmax (rows live in 16-lane groups; butterfly reduce)
#pragma unroll
    for (int j = 0; j < 4; ++j) {
      u64 word = mw[w * 16 + lq * 4 + j];
      float mx = -3e38f;
#pragma unroll
      for (int kb = 0; kb < 4; ++kb) {
        float v = s[kb][j];
        if (!((word >> (kb * 16 + lr)) & 1ull)) v = -1e9f;
        s[kb][j] = v;
        mx = fmaxf(mx, v);
      }
#pragma unroll
      for (int mk = 1; mk < 16; mk <<= 1) mx = fmaxf(mx, __shfl_xor(mx, mk));
      float mn = fmaxf(mr[j], mx);
      float scale = __expf(mr[j] - mn);
      mr[j] = mn;
      float ps = 0.f;
#pragma unroll
      for (int kb = 0; kb < 4; ++kb) {
        float p = __expf(s[kb][j] - mn);
        s[kb][j] = p;
        ps += p;
      }
#pragma unroll
      for (int mk = 1; mk < 16; mk <<= 1) ps += __shfl_xor(ps, mk);
      lsum[j] = lsum[j] * scale + ps;
#pragma unroll
      for (int dv = 0; dv < 4; ++dv) o[dv][j] *= scale;
    }
    // P (C-layout) -> per-wave LDS -> A-layout frags
    u16* pw = &Ps[w][0];
#pragma unroll
    for (int j = 0; j < 4; ++j)
#pragma unroll
      for (int kb = 0; kb < 4; ++kb)
        pw[(lq * 4 + j) * 72 + kb * 16 + lr] = f2bf(s[kb][j]);
#pragma unroll
    for (int kk = 0; kk < 2; ++kk) {
      bf16x8 pa = frag8(&pw[lr * 72 + kk * 32 + lq * 8]);
#pragma unroll
      for (int dv = 0; dv < 4; ++dv) {
        bf16x8 vf = frag8(&Vs[(dv * 16 + lr) * 72 + kk * 32 + lq * 8]);
        o[dv] = MFMA(pa, vf, o[dv]);
      }
    }
    __syncthreads();
  }
  // normalize + store concat layout [B,S,H*64] bf16
  const int b = bh >> 4, h = bh & 15;
#pragma unroll
  for (int j = 0; j < 4; ++j) {
    float inv = 1.f / lsum[j];
    int srow = q0 + w * 16 + lq * 4 + j;
    int base = (b * 1024 + srow) * 1024 + h * 64;
#pragma unroll
    for (int dv = 0; dv < 4; ++dv) Oc[base + dv * 16 + lr] = f2bf(o[dv][j] * inv);
  }
}

// ---------------- final projection: Oc[4096x1024]bf16 @ WpT[n][k]bf16 + bp -> fp32 ----
// 64x128 tile, global_load_lds staging
__global__ __launch_bounds__(256) void final_kernel(
    const u16* __restrict__ A, const u16* __restrict__ Bt,
    const float* __restrict__ bias, float* __restrict__ out) {
  __shared__ alignas(16) u16 As[64 * 32];
  __shared__ alignas(16) u16 Bs[128 * 32];
  const int m0 = blockIdx.x * 64, n0 = blockIdx.y * 128;
  const int t = threadIdx.x, w = t >> 6, l = t & 63;
  const int wr = w >> 1, wc = w & 1, lr = l & 15, lq = l >> 4;
  const int srow = l >> 2, scol = (l & 3) * 8;
  f32x4 acc[2][4];
#pragma unroll
  for (int i = 0; i < 2; ++i)
#pragma unroll
    for (int j = 0; j < 4; ++j) acc[i][j] = (f32x4){0.f, 0.f, 0.f, 0.f};

  for (int ks = 0; ks < 32; ++ks) {
    const int k0 = ks * 32;
    // As: 4 chunks (wave w -> chunk w); Bs: 8 chunks (wave w -> 2w, 2w+1)
    gload16(&As[w * 512], &A[(m0 + w * 16 + srow) * 1024 + k0 + scol]);
#pragma unroll
    for (int i = 0; i < 2; ++i) {
      const int ci = w * 2 + i;
      gload16(&Bs[ci * 512], &Bt[(n0 + ci * 16 + srow) * 1024 + k0 + scol]);
    }
    __syncthreads();
    bf16x8 a[2];
#pragma unroll
    for (int mi = 0; mi < 2; ++mi)
      a[mi] = frag8(&As[(wr * 32 + mi * 16 + lr) * 32 + lq * 8]);
#pragma unroll
    for (int nj = 0; nj < 4; ++nj) {
      bf16x8 bfr = frag8(&Bs[(wc * 64 + nj * 16 + lr) * 32 + lq * 8]);
#pragma unroll
      for (int mi = 0; mi < 2; ++mi) acc[mi][nj] = MFMA(a[mi], bfr, acc[mi][nj]);
    }
    __syncthreads();
  }
#pragma unroll
  for (int nj = 0; nj < 4; ++nj) {
    int n = n0 + wc * 64 + nj * 16 + lr;
    float bb = bias[n];
#pragma unroll
    for (int mi = 0; mi < 2; ++mi)
#pragma unroll
      for (int j = 0; j < 4; ++j) {
        int m = m0 + wr * 32 + mi * 16 + lq * 4 + j;
        out[m * 1024 + n] = acc[mi][nj][j] + bb;
      }
  }
}

// ---------------- launch ----------------
// ws layout (MiB): Qh 0, Ql 8, Kh 16, Kl 24, Vt 32, Oc 40 (Xkh aliases Oc),
//   wqh 48, wql 50, wkh 52, wkl 54, wvh 56, wph 58, Xkl 60, Xvh 68, mp 76 (+128KB)
// Xqh/Xql live in d_out (16 MiB), dead before final_kernel writes it.
extern "C" void kernel_launch(void* const* d_in, const int* in_sizes, int n_in,
                              void* d_out, int out_size, void* d_ws, size_t ws_size,
                              hipStream_t stream) {
  (void)in_sizes; (void)n_in; (void)out_size; (void)ws_size;
  const float* querys = (const float*)d_in[0];
  const float* keys = (const float*)d_in[1];
  const float* values = (const float*)d_in[2];
  const int* mask = (const int*)d_in[3];
  const float* Wq = (const float*)d_in[4];
  const float* bq = (const float*)d_in[5];
  const float* Wk = (const float*)d_in[6];
  const float* bk = (const float*)d_in[7];
  const float* Wv = (const float*)d_in[8];
  const float* bv = (const float*)d_in[9];
  const float* Wp = (const float*)d_in[10];
  const float* bp = (const float*)d_in[11];
  float* out = (float*)d_out;

  char* ws = (char*)d_ws;
  const size_t MB = 1024ull * 1024ull;
  u16* Qh = (u16*)(ws + 0 * MB);
  u16* Ql = (u16*)(ws + 8 * MB);
  u16* Kh = (u16*)(ws + 16 * MB);
  u16* Kl = (u16*)(ws + 24 * MB);
  u16* Vt = (u16*)(ws + 32 * MB);
  u16* Oc = (u16*)(ws + 40 * MB);
  u16* wqh = (u16*)(ws + 48 * MB);
  u16* wql = (u16*)(ws + 50 * MB);
  u16* wkh = (u16*)(ws + 52 * MB);
  u16* wkl = (u16*)(ws + 54 * MB);
  u16* wvh = (u16*)(ws + 56 * MB);
  u16* wph = (u16*)(ws + 58 * MB);
  u16* Xkl = (u16*)(ws + 60 * MB);
  u16* Xvh = (u16*)(ws + 68 * MB);
  u64* mp = (u64*)(ws + 76 * MB);
  u16* Xqh = (u16*)d_out;                  // dead before final_kernel
  u16* Xql = (u16*)((char*)d_out + 8 * MB);
  u16* Xkh = Oc;                           // dead before attn writes Oc

  prep_weights<<<dim3(16, 16, 4), 256, 0, stream>>>(Wq, Wk, Wv, Wp, wqh, wql, wkh,
                                                    wkl, wvh, wph);
  pack_mask<<<dim3(4096), 256, 0, stream>>>(mask, mp);
  split_x<<<dim3(2048, 3), 256, 0, stream>>>(querys, keys, values, Xqh, Xql, Xkh,
                                             Xkl, Xvh);
  proj_fused<<<dim3(32, 8, 3), 256, 0, stream>>>(Xqh, Xql, Xkh, Xkl, Xvh, wqh, wql,
                                                 wkh, wkl, wvh, bq, bk, bv, Qh, Ql,
                                                 Kh, Kl, Vt);
  attn_kernel<<<dim3(1024), 256, 0, stream>>>(Qh, Ql, Kh, Kl, Vt, mp, Oc);
  final_kernel<<<dim3(64, 8), 256, 0, stream>>>(Oc, wph, bp, out);
}

// Round 6
// 318.173 us; speedup vs baseline: 1.6714x; 1.6714x over previous
//
#include <hip/hip_runtime.h>
#include <hip/hip_bf16.h>

typedef unsigned short u16;
typedef unsigned long long u64;
typedef __attribute__((ext_vector_type(4))) float f32x4;
typedef __attribute__((ext_vector_type(8))) __bf16 bf16x8;
typedef __attribute__((ext_vector_type(8))) u16 u16x8;

#define DEV __device__ __forceinline__
#define MFMA(a, b, c) __builtin_amdgcn_mfma_f32_16x16x32_bf16(a, b, c, 0, 0, 0)

// B=4, S=1024, D=1024, H=16, DK=DV=64, M=B*S=4096

DEV u16 f2bf(float x) {
  unsigned u = __builtin_bit_cast(unsigned, x);
  u += 0x7fffu + ((u >> 16) & 1u);
  return (u16)(u >> 16);
}
DEV float bf2f(u16 h) {
  unsigned u = ((unsigned)h) << 16;
  return __builtin_bit_cast(float, u);
}
DEV bf16x8 frag8(const u16* p) {
  return __builtin_bit_cast(bf16x8, *(const u16x8*)p);
}
// async global->LDS, 16B per lane; lds base must be the wave-uniform chunk base
DEV void gload16(u16* lds, const u16* g) {
  __builtin_amdgcn_global_load_lds((const __attribute__((address_space(1))) void*)g,
                                   (__attribute__((address_space(3))) void*)lds, 16, 0, 0);
}

// ---------------- prep: transpose + hi/lo-split weights into [N][K] bf16 ----------------
__global__ __launch_bounds__(256) void prep_weights(
    const float* __restrict__ Wq, const float* __restrict__ Wk,
    const float* __restrict__ Wv, const float* __restrict__ Wp,
    u16* __restrict__ wqh, u16* __restrict__ wql,
    u16* __restrict__ wkh, u16* __restrict__ wkl,
    u16* __restrict__ wvh, u16* __restrict__ wph) {
  __shared__ float tile[64][65];
  const int k0 = blockIdx.x * 64;
  const int h = blockIdx.y;
  const int z = blockIdx.z;
  const float* src;
  u16* dhi;
  u16* dlo = nullptr;
  int hs, rs;
  if (z == 0)      { src = Wq; dhi = wqh; dlo = wql; hs = 65536; rs = 64; }
  else if (z == 1) { src = Wk; dhi = wkh; dlo = wkl; hs = 65536; rs = 64; }
  else if (z == 2) { src = Wv; dhi = wvh;            hs = 65536; rs = 64; }
  else             { src = Wp; dhi = wph;            hs = 64;    rs = 1024; }
  const int t = threadIdx.x;
#pragma unroll
  for (int i = 0; i < 16; ++i) {
    int kk = i * 4 + (t >> 6), nn = t & 63;
    tile[kk][nn] = src[h * hs + (k0 + kk) * rs + nn];
  }
  __syncthreads();
#pragma unroll
  for (int i = 0; i < 16; ++i) {
    int nn = i * 4 + (t >> 6), kk = t & 63;
    float x = tile[kk][nn];
    u16 hi = f2bf(x);
    int idx = (h * 64 + nn) * 1024 + k0 + kk;
    dhi[idx] = hi;
    if (dlo) dlo[idx] = f2bf(x - bf2f(hi));
  }
}

// ---------------- prep: pack mask rows into u64 bit-words ----------------
__global__ __launch_bounds__(256) void pack_mask(const int* __restrict__ mask,
                                                 u64* __restrict__ mp) {
  int g = blockIdx.x * 4 + (threadIdx.x >> 6);  // word id 0..16383
  int lane = threadIdx.x & 63;
  int v = mask[(g >> 4) * 1024 + (g & 15) * 64 + lane];
  u64 bits = __ballot(v != 0);
  if (lane == 0) mp[g] = bits;
}

// ---------------- prep: split activations fp32 -> hi/lo bf16 ----------------
// z=0: querys -> Xqh/Xql ; z=1: keys -> Xkh/Xkl ; z=2: values -> Xvh (hi only)
__global__ __launch_bounds__(256) void split_x(
    const float* __restrict__ q, const float* __restrict__ k,
    const float* __restrict__ v, u16* __restrict__ qh, u16* __restrict__ ql,
    u16* __restrict__ kh, u16* __restrict__ kl, u16* __restrict__ vh) {
  const int z = blockIdx.y;
  const float* src = (z == 0) ? q : (z == 1) ? k : v;
  u16* dh = (z == 0) ? qh : (z == 1) ? kh : vh;
  u16* dl = (z == 0) ? ql : kl;
  const bool split = (z < 2);
  const long base = (long)(blockIdx.x * 256 + threadIdx.x) * 8;
  f32x4 v0 = *(const f32x4*)&src[base];
  f32x4 v1 = *(const f32x4*)&src[base + 4];
  u16x8 hi, lo;
#pragma unroll
  for (int e = 0; e < 4; ++e) {
    u16 h0 = f2bf(v0[e]), h1 = f2bf(v1[e]);
    hi[e] = h0;
    hi[4 + e] = h1;
    lo[e] = f2bf(v0[e] - bf2f(h0));
    lo[4 + e] = f2bf(v1[e] - bf2f(h1));
  }
  *(u16x8*)&dh[base] = hi;
  if (split) *(u16x8*)&dl[base] = lo;
}

// ---------------- fused QKV projection GEMM (global_load_lds staging) ----------------
// z=0: Xq @ Wq -> split Qh/Ql ; z=1: Xk @ Wk -> split Kh/Kl
// z=2: Xv @ Wv -> plain bf16 transposed Vt[bh][dv][s]
// launch_bounds (256,3): 170-reg budget -- (256,4)'s 128 budget spilled acc to
// scratch (round 5: 1 GB WRITE_SIZE, MfmaUtil 7.7%). 3 blocks/CU via LDS 32KB.
__global__ __launch_bounds__(256, 3) void proj_fused(
    const u16* __restrict__ Xqh, const u16* __restrict__ Xql,
    const u16* __restrict__ Xkh, const u16* __restrict__ Xkl,
    const u16* __restrict__ Xvh, const u16* __restrict__ wqh,
    const u16* __restrict__ wql, const u16* __restrict__ wkh,
    const u16* __restrict__ wkl, const u16* __restrict__ wvh,
    const float* __restrict__ bq, const float* __restrict__ bk,
    const float* __restrict__ bv, u16* __restrict__ Qh, u16* __restrict__ Ql,
    u16* __restrict__ Kh, u16* __restrict__ Kl, u16* __restrict__ Vt) {
  __shared__ alignas(16) u16 Ah[128 * 32];
  __shared__ alignas(16) u16 Al[128 * 32];
  __shared__ alignas(16) u16 Bh[128 * 32];
  __shared__ alignas(16) u16 Bl[128 * 32];
  const int z = blockIdx.z;
  const bool split = (z < 2);
  const u16* Ah_src = (z == 0) ? Xqh : (z == 1) ? Xkh : Xvh;
  const u16* Al_src = (z == 0) ? Xql : Xkl;
  const u16* Bh_src = (z == 0) ? wqh : (z == 1) ? wkh : wvh;
  const u16* Bl_src = (z == 0) ? wql : wkl;
  const float* bias = (z == 0) ? bq : (z == 1) ? bk : bv;
  u16* Oh = (z == 0) ? Qh : (z == 1) ? Kh : Vt;
  u16* Ol = (z == 0) ? Ql : Kl;

  const int m0 = blockIdx.x * 128, n0 = blockIdx.y * 128;
  const int t = threadIdx.x, w = t >> 6, l = t & 63;
  const int wr = w >> 1, wc = w & 1, lr = l & 15, lq = l >> 4;
  const int srow = l >> 2, scol = (l & 3) * 8;  // staging lane coords
  f32x4 acc[4][4];
#pragma unroll
  for (int i = 0; i < 4; ++i)
#pragma unroll
    for (int j = 0; j < 4; ++j) acc[i][j] = (f32x4){0.f, 0.f, 0.f, 0.f};

  for (int ks = 0; ks < 32; ++ks) {
    const int k0 = ks * 32;
    // stage: 8KB/tile = 8 chunks of 1KB; wave w issues chunks {2w, 2w+1}
#pragma unroll
    for (int i = 0; i < 2; ++i) {
      const int ci = w * 2 + i;
      const int rr = ci * 16 + srow;
      gload16(&Ah[ci * 512], &Ah_src[(m0 + rr) * 1024 + k0 + scol]);
      gload16(&Bh[ci * 512], &Bh_src[(n0 + rr) * 1024 + k0 + scol]);
      if (split) {
        gload16(&Al[ci * 512], &Al_src[(m0 + rr) * 1024 + k0 + scol]);
        gload16(&Bl[ci * 512], &Bl_src[(n0 + rr) * 1024 + k0 + scol]);
      }
    }
    __syncthreads();
    bf16x8 ah[4], al[4];
#pragma unroll
    for (int mi = 0; mi < 4; ++mi) {
      int row = wr * 64 + mi * 16 + lr;
      ah[mi] = frag8(&Ah[row * 32 + lq * 8]);
      if (split) al[mi] = frag8(&Al[row * 32 + lq * 8]);
    }
    if (split) {
#pragma unroll
      for (int nj = 0; nj < 4; ++nj) {
        int col = wc * 64 + nj * 16 + lr;
        bf16x8 bh = frag8(&Bh[col * 32 + lq * 8]);
        bf16x8 bl = frag8(&Bl[col * 32 + lq * 8]);
#pragma unroll
        for (int mi = 0; mi < 4; ++mi) {
          acc[mi][nj] = MFMA(ah[mi], bh, acc[mi][nj]);
          acc[mi][nj] = MFMA(ah[mi], bl, acc[mi][nj]);
          acc[mi][nj] = MFMA(al[mi], bh, acc[mi][nj]);
        }
      }
    } else {
#pragma unroll
      for (int nj = 0; nj < 4; ++nj) {
        int col = wc * 64 + nj * 16 + lr;
        bf16x8 bh = frag8(&Bh[col * 32 + lq * 8]);
#pragma unroll
        for (int mi = 0; mi < 4; ++mi) acc[mi][nj] = MFMA(ah[mi], bh, acc[mi][nj]);
      }
    }
    __syncthreads();
  }
  // epilogue: add bias, split-store (z<2) or transpose-store (z==2)
#pragma unroll
  for (int nj = 0; nj < 4; ++nj) {
    int n = n0 + wc * 64 + nj * 16 + lr;
    float bb = bias[n];
    int h = n >> 6, dk = n & 63;
#pragma unroll
    for (int mi = 0; mi < 4; ++mi) {
#pragma unroll
      for (int j = 0; j < 4; ++j) {
        int m = m0 + wr * 64 + mi * 16 + lq * 4 + j;
        int b = m >> 10, s = m & 1023;
        float x = acc[mi][nj][j] + bb;
        if (split) {
          int idx = ((b * 16 + h) * 1024 + s) * 64 + dk;
          u16 hh = f2bf(x);
          Oh[idx] = hh;
          Ol[idx] = f2bf(x - bf2f(hh));
        } else {
          int idx = ((b * 16 + h) * 64 + dk) * 1024 + s;
          Oh[idx] = f2bf(x);
        }
      }
    }
  }
}

// ---------------- flash attention: 1 block per (b,h, 64-row q-tile) ----------------
// T14 async-STAGE: issue tile t+1 global loads under tile t compute.
// launch_bounds (256,2): 256-reg budget so the prefetch regs (rKh/rKl/rVs ~48
// VGPR) never spill; residency stays reg/LDS-limited at ~3-4 blocks/CU.
__global__ __launch_bounds__(256, 2) void attn_kernel(
    const u16* __restrict__ Qh, const u16* __restrict__ Ql,
    const u16* __restrict__ Kh, const u16* __restrict__ Kl,
    const u16* __restrict__ Vt, const u64* __restrict__ mp,
    u16* __restrict__ Oc) {
  __shared__ alignas(16) u16 Ks_h[64 * 72];
  __shared__ alignas(16) u16 Ks_l[64 * 72];
  __shared__ alignas(16) u16 Vs[64 * 72];
  __shared__ alignas(16) u16 Ps[4][16 * 72];
  __shared__ u64 mw[64];
  const int bid = blockIdx.x;
  const int bh = bid >> 4, qt = bid & 15, q0 = qt * 64;
  const int t = threadIdx.x, w = t >> 6, l = t & 63;
  const int lr = l & 15, lq = l >> 4;
  const int qrow = q0 + w * 16 + lr;
  const int rr = t >> 2, c0 = (t & 3) * 8;

  bf16x8 qh[2], qlo[2];
#pragma unroll
  for (int d = 0; d < 2; ++d) {
    int off = (bh * 1024 + qrow) * 64 + d * 32 + lq * 8;
    qh[d] = frag8(&Qh[off]);
    qlo[d] = frag8(&Ql[off]);
  }
  f32x4 o[4];
#pragma unroll
  for (int dv = 0; dv < 4; ++dv) o[dv] = (f32x4){0.f, 0.f, 0.f, 0.f};
  float mr[4] = {-1e30f, -1e30f, -1e30f, -1e30f};
  float lsum[4] = {0.f, 0.f, 0.f, 0.f};

  // prefetch registers for the next tile
  u16x8 rKh[2], rKl[2], rVs[2];
  u64 rMw = 0;
  auto issue = [&](int kt) {
    const int k0 = kt * 64;
#pragma unroll
    for (int half = 0; half < 2; ++half) {
      int c = c0 + half * 32;
      rKh[half] = *(const u16x8*)&Kh[(bh * 1024 + k0 + rr) * 64 + c];
      rKl[half] = *(const u16x8*)&Kl[(bh * 1024 + k0 + rr) * 64 + c];
      rVs[half] = *(const u16x8*)&Vt[(bh * 64 + rr) * 1024 + k0 + c];
    }
    if (t < 64) rMw = mp[(q0 + t) * 16 + kt];
  };

  issue(0);
  for (int kt = 0; kt < 16; ++kt) {
    // write phase: prefetched regs -> LDS
#pragma unroll
    for (int half = 0; half < 2; ++half) {
      int c = c0 + half * 32;
      *(u16x8*)&Ks_h[rr * 72 + c] = rKh[half];
      *(u16x8*)&Ks_l[rr * 72 + c] = rKl[half];
      *(u16x8*)&Vs[rr * 72 + c] = rVs[half];
    }
    if (t < 64) mw[t] = rMw;
    __syncthreads();
    if (kt < 15) issue(kt + 1);  // latency hides under compute below
    // scores: S[16q x 64key] via 3-term split MFMA
    f32x4 s[4];
#pragma unroll
    for (int kb = 0; kb < 4; ++kb) {
      f32x4 a = (f32x4){0.f, 0.f, 0.f, 0.f};
#pragma unroll
      for (int d = 0; d < 2; ++d) {
        bf16x8 kfh = frag8(&Ks_h[(kb * 16 + lr) * 72 + d * 32 + lq * 8]);
        bf16x8 kfl = frag8(&Ks_l[(kb * 16 + lr) * 72 + d * 32 + lq * 8]);
        a = MFMA(qh[d], kfh, a);
        a = MFMA(qh[d], kfl, a);
        a = MFMA(qlo[d], kfh, a);
      }
      s[kb] = a;
    }
    // mask + online softmax (rows live in 16-lane groups; butterfly reduce)
#pragma unroll
    for (int j = 0; j < 4; ++j) {
      u64 word = mw[w * 16 + lq * 4 + j];
      float mx = -3e38f;
#pragma unroll
      for (int kb = 0; kb < 4; ++kb) {
        float v = s[kb][j];
        if (!((word >> (kb * 16 + lr)) & 1ull)) v = -1e9f;
        s[kb][j] = v;
        mx = fmaxf(mx, v);
      }
#pragma unroll
      for (int mk = 1; mk < 16; mk <<= 1) mx = fmaxf(mx, __shfl_xor(mx, mk));
      float mn = fmaxf(mr[j], mx);
      float scale = __expf(mr[j] - mn);
      mr[j] = mn;
      float ps = 0.f;
#pragma unroll
      for (int kb = 0; kb < 4; ++kb) {
        float p = __expf(s[kb][j] - mn);
        s[kb][j] = p;
        ps += p;
      }
#pragma unroll
      for (int mk = 1; mk < 16; mk <<= 1) ps += __shfl_xor(ps, mk);
      lsum[j] = lsum[j] * scale + ps;
#pragma unroll
      for (int dv = 0; dv < 4; ++dv) o[dv][j] *= scale;
    }
    // P (C-layout) -> per-wave LDS -> A-layout frags
    u16* pw = &Ps[w][0];
#pragma unroll
    for (int j = 0; j < 4; ++j)
#pragma unroll
      for (int kb = 0; kb < 4; ++kb)
        pw[(lq * 4 + j) * 72 + kb * 16 + lr] = f2bf(s[kb][j]);
#pragma unroll
    for (int kk = 0; kk < 2; ++kk) {
      bf16x8 pa = frag8(&pw[lr * 72 + kk * 32 + lq * 8]);
#pragma unroll
      for (int dv = 0; dv < 4; ++dv) {
        bf16x8 vf = frag8(&Vs[(dv * 16 + lr) * 72 + kk * 32 + lq * 8]);
        o[dv] = MFMA(pa, vf, o[dv]);
      }
    }
    __syncthreads();
  }
  // normalize + store concat layout [B,S,H*64] bf16
  const int b = bh >> 4, h = bh & 15;
#pragma unroll
  for (int j = 0; j < 4; ++j) {
    float inv = 1.f / lsum[j];
    int srow = q0 + w * 16 + lq * 4 + j;
    int base = (b * 1024 + srow) * 1024 + h * 64;
#pragma unroll
    for (int dv = 0; dv < 4; ++dv) Oc[base + dv * 16 + lr] = f2bf(o[dv][j] * inv);
  }
}

// ---------------- final projection: Oc[4096x1024]bf16 @ WpT[n][k]bf16 + bp -> fp32 ----
// 64x128 tile, global_load_lds staging
__global__ __launch_bounds__(256) void final_kernel(
    const u16* __restrict__ A, const u16* __restrict__ Bt,
    const float* __restrict__ bias, float* __restrict__ out) {
  __shared__ alignas(16) u16 As[64 * 32];
  __shared__ alignas(16) u16 Bs[128 * 32];
  const int m0 = blockIdx.x * 64, n0 = blockIdx.y * 128;
  const int t = threadIdx.x, w = t >> 6, l = t & 63;
  const int wr = w >> 1, wc = w & 1, lr = l & 15, lq = l >> 4;
  const int srow = l >> 2, scol = (l & 3) * 8;
  f32x4 acc[2][4];
#pragma unroll
  for (int i = 0; i < 2; ++i)
#pragma unroll
    for (int j = 0; j < 4; ++j) acc[i][j] = (f32x4){0.f, 0.f, 0.f, 0.f};

  for (int ks = 0; ks < 32; ++ks) {
    const int k0 = ks * 32;
    // As: 4 chunks (wave w -> chunk w); Bs: 8 chunks (wave w -> 2w, 2w+1)
    gload16(&As[w * 512], &A[(m0 + w * 16 + srow) * 1024 + k0 + scol]);
#pragma unroll
    for (int i = 0; i < 2; ++i) {
      const int ci = w * 2 + i;
      gload16(&Bs[ci * 512], &Bt[(n0 + ci * 16 + srow) * 1024 + k0 + scol]);
    }
    __syncthreads();
    bf16x8 a[2];
#pragma unroll
    for (int mi = 0; mi < 2; ++mi)
      a[mi] = frag8(&As[(wr * 32 + mi * 16 + lr) * 32 + lq * 8]);
#pragma unroll
    for (int nj = 0; nj < 4; ++nj) {
      bf16x8 bfr = frag8(&Bs[(wc * 64 + nj * 16 + lr) * 32 + lq * 8]);
#pragma unroll
      for (int mi = 0; mi < 2; ++mi) acc[mi][nj] = MFMA(a[mi], bfr, acc[mi][nj]);
    }
    __syncthreads();
  }
#pragma unroll
  for (int nj = 0; nj < 4; ++nj) {
    int n = n0 + wc * 64 + nj * 16 + lr;
    float bb = bias[n];
#pragma unroll
    for (int mi = 0; mi < 2; ++mi)
#pragma unroll
      for (int j = 0; j < 4; ++j) {
        int m = m0 + wr * 32 + mi * 16 + lq * 4 + j;
        out[m * 1024 + n] = acc[mi][nj][j] + bb;
      }
  }
}

// ---------------- launch ----------------
// ws layout (MiB): Qh 0, Ql 8, Kh 16, Kl 24, Vt 32, Oc 40 (Xkh aliases Oc),
//   wqh 48, wql 50, wkh 52, wkl 54, wvh 56, wph 58, Xkl 60, Xvh 68, mp 76 (+128KB)
// Xqh/Xql live in d_out (16 MiB), dead before final_kernel writes it.
extern "C" void kernel_launch(void* const* d_in, const int* in_sizes, int n_in,
                              void* d_out, int out_size, void* d_ws, size_t ws_size,
                              hipStream_t stream) {
  (void)in_sizes; (void)n_in; (void)out_size; (void)ws_size;
  const float* querys = (const float*)d_in[0];
  const float* keys = (const float*)d_in[1];
  const float* values = (const float*)d_in[2];
  const int* mask = (const int*)d_in[3];
  const float* Wq = (const float*)d_in[4];
  const float* bq = (const float*)d_in[5];
  const float* Wk = (const float*)d_in[6];
  const float* bk = (const float*)d_in[7];
  const float* Wv = (const float*)d_in[8];
  const float* bv = (const float*)d_in[9];
  const float* Wp = (const float*)d_in[10];
  const float* bp = (const float*)d_in[11];
  float* out = (float*)d_out;

  char* ws = (char*)d_ws;
  const size_t MB = 1024ull * 1024ull;
  u16* Qh = (u16*)(ws + 0 * MB);
  u16* Ql = (u16*)(ws + 8 * MB);
  u16* Kh = (u16*)(ws + 16 * MB);
  u16* Kl = (u16*)(ws + 24 * MB);
  u16* Vt = (u16*)(ws + 32 * MB);
  u16* Oc = (u16*)(ws + 40 * MB);
  u16* wqh = (u16*)(ws + 48 * MB);
  u16* wql = (u16*)(ws + 50 * MB);
  u16* wkh = (u16*)(ws + 52 * MB);
  u16* wkl = (u16*)(ws + 54 * MB);
  u16* wvh = (u16*)(ws + 56 * MB);
  u16* wph = (u16*)(ws + 58 * MB);
  u16* Xkl = (u16*)(ws + 60 * MB);
  u16* Xvh = (u16*)(ws + 68 * MB);
  u64* mp = (u64*)(ws + 76 * MB);
  u16* Xqh = (u16*)d_out;                  // dead before final_kernel
  u16* Xql = (u16*)((char*)d_out + 8 * MB);
  u16* Xkh = Oc;                           // dead before attn writes Oc

  prep_weights<<<dim3(16, 16, 4), 256, 0, stream>>>(Wq, Wk, Wv, Wp, wqh, wql, wkh,
                                                    wkl, wvh, wph);
  pack_mask<<<dim3(4096), 256, 0, stream>>>(mask, mp);
  split_x<<<dim3(2048, 3), 256, 0, stream>>>(querys, keys, values, Xqh, Xql, Xkh,
                                             Xkl, Xvh);
  proj_fused<<<dim3(32, 8, 3), 256, 0, stream>>>(Xqh, Xql, Xkh, Xkl, Xvh, wqh, wql,
                                                 wkh, wkl, wvh, bq, bk, bv, Qh, Ql,
                                                 Kh, Kl, Vt);
  attn_kernel<<<dim3(1024), 256, 0, stream>>>(Qh, Ql, Kh, Kl, Vt, mp, Oc);
  final_kernel<<<dim3(64, 8), 256, 0, stream>>>(Oc, wph, bp, out);
}